// Round 2
// baseline (348.724 us; speedup 1.0000x reference)
//
#include <hip/hip_runtime.h>

#define G_GROUPS 512
#define CNT      8192
#define S_PAIRS  8192
#define BLOCK    1024
#define WAVES    (BLOCK / 64)        // 16
#define PPT      (S_PAIRS / BLOCK)   // 8 pairs per thread
#define RPT      (CNT / BLOCK)       // 8 records per thread per tensor

__global__ __launch_bounds__(BLOCK) void rgn_loss_kernel(
    const float* __restrict__ inputs,
    const float* __restrict__ target,
    const int*   __restrict__ left,
    const int*   __restrict__ right,
    float*       __restrict__ out)
{
    // CA-row table, one tensor at a time: 8192 x float4 = 128 KiB.
    __shared__ float4 tab4[CNT];
    __shared__ float  red[WAVES];

    const int tid   = threadIdx.x;
    const int lane  = tid & 63;
    const int wid   = tid >> 6;
    const int g     = blockIdx.x;
    const int gbase = g * CNT;

    // ---- Pair indices: 16 coalesced loads, fly under the input stage ----
    const size_t pbase = (size_t)g * S_PAIRS;
    int li[PPT], ri[PPT];
    #pragma unroll
    for (int i = 0; i < PPT; ++i) {
        li[i] = left [pbase + tid + i * BLOCK] - gbase;   // group-local by construction
        ri[i] = right[pbase + tid + i * BLOCK] - gbase;
    }

    // ---- Stage inputs: reg-staged streaming (NOT global_load_lds).
    //      16 B per record at byte 36r+12 (4B-aligned; memcpy lets the
    //      compiler pick dwordx4-unaligned or split loads — both correct).
    //      8 loads/thread in flight -> 64 KiB outstanding per CU.
    float4 iv[RPT];
    #pragma unroll
    for (int k = 0; k < RPT; ++k) {
        const float* p = inputs + (size_t)(gbase + tid + k * BLOCK) * 9 + 3;
        __builtin_memcpy(&iv[k], p, 16);
    }
    #pragma unroll
    for (int k = 0; k < RPT; ++k)
        tab4[tid + k * BLOCK] = iv[k];     // lane-contiguous ds_write_b128
    __syncthreads();                       // inputs table published

    // ---- Issue ALL target loads NOW; they complete under the d_in gather.
    float4 tv[RPT];
    #pragma unroll
    for (int k = 0; k < RPT; ++k) {
        const float* p = target + (size_t)(gbase + tid + k * BLOCK) * 9 + 3;
        __builtin_memcpy(&tv[k], p, 16);
    }
    asm volatile("" ::: "memory");         // pin loads before the gather

    // ---- Gather d_in, park in VGPRs ----
    float din[PPT];
    #pragma unroll
    for (int i = 0; i < PPT; ++i) {
        const float4 L = tab4[li[i]];
        const float4 R = tab4[ri[i]];
        const float dx = L.x - R.x;
        const float dy = L.y - R.y;
        const float dz = L.z - R.z;
        din[i] = sqrtf(dx * dx + dy * dy + dz * dz);
    }
    __syncthreads();                       // all gather reads done before overwrite

    // ---- Publish target table (loads long since landed) ----
    #pragma unroll
    for (int k = 0; k < RPT; ++k)
        tab4[tid + k * BLOCK] = tv[k];
    __syncthreads();

    // ---- Gather d_tg, accumulate squared difference ----
    float acc = 0.0f;
    #pragma unroll
    for (int i = 0; i < PPT; ++i) {
        const float4 L = tab4[li[i]];
        const float4 R = tab4[ri[i]];
        const float dx = L.x - R.x;
        const float dy = L.y - R.y;
        const float dz = L.z - R.z;
        const float d  = din[i] - sqrtf(dx * dx + dy * dy + dz * dz);
        acc += d * d;
    }

    // ---- Block reduction -> one atomic ----
    #pragma unroll
    for (int off = 32; off > 0; off >>= 1)
        acc += __shfl_down(acc, off);
    if (lane == 0) red[wid] = acc;
    __syncthreads();
    if (wid == 0) {
        float v = (lane < WAVES) ? red[lane] : 0.0f;
        #pragma unroll
        for (int off = 8; off > 0; off >>= 1)
            v += __shfl_down(v, off);
        if (lane == 0)
            atomicAdd(out, v * (1.0f / ((float)G_GROUPS * (float)S_PAIRS)));
    }
}

extern "C" void kernel_launch(void* const* d_in, const int* in_sizes, int n_in,
                              void* d_out, int out_size, void* d_ws, size_t ws_size,
                              hipStream_t stream) {
    const float* inputs = (const float*)d_in[0];
    const float* target = (const float*)d_in[1];
    const int*   left   = (const int*)d_in[2];
    const int*   right  = (const int*)d_in[3];
    float*       out    = (float*)d_out;

    hipMemsetAsync(out, 0, sizeof(float), stream);   // graph-capture safe
    rgn_loss_kernel<<<G_GROUPS, BLOCK, 0, stream>>>(inputs, target, left, right, out);
}